// Round 1
// baseline (22.755 us; speedup 1.0000x reference)
//
#include <hip/hip_runtime.h>

#define R 128
#define C 256
#define P 7
#define HW 64

__global__ void roi_pool_kernel(const float* __restrict__ x,
                                const int* __restrict__ rois,
                                float* __restrict__ out) {
    int tid = blockIdx.x * blockDim.x + threadIdx.x;
    const int total = R * C * P * P;
    if (tid >= total) return;

    int px = tid % P;
    int py = (tid / P) % P;
    int c  = (tid / (P * P)) % C;
    int r  = tid / (P * P * C);

    int rx = rois[r * 4 + 0];
    int ry = rois[r * 4 + 1];
    int rw = rois[r * 4 + 2];
    int rh = rois[r * 4 + 3];

    float rlx = (float)rw / 7.0f;
    float rly = (float)rh / 7.0f;

    // Match JAX exactly: floor(coord + ix*rl) with separate rn mul + rn add
    // (avoid fp-contract changing the rounding at integer boundaries).
    int sx = (int)floorf(__fadd_rn((float)rx, __fmul_rn((float)px, rlx)));
    int ex = sx + (int)rlx;          // + floor(rl); rl > 0 so trunc == floor
    sx = max(sx, 0);
    ex = min(ex, HW);

    int sy = (int)floorf(__fadd_rn((float)ry, __fmul_rn((float)py, rly)));
    int ey = sy + (int)rly;
    sy = max(sy, 0);
    ey = min(ey, HW);

    const float* xc = x + (size_t)c * HW * HW;
    float m = -3.402823466e38f;  // finfo(float32).min
    for (int iy = sy; iy < ey; ++iy) {
        const float* row = xc + iy * HW;
        for (int ix = sx; ix < ex; ++ix) {
            m = fmaxf(m, row[ix]);
        }
    }
    out[tid] = m;
}

extern "C" void kernel_launch(void* const* d_in, const int* in_sizes, int n_in,
                              void* d_out, int out_size, void* d_ws, size_t ws_size,
                              hipStream_t stream) {
    const float* x = (const float*)d_in[0];
    const int* rois = (const int*)d_in[1];
    float* out = (float*)d_out;

    const int total = R * C * P * P;  // 1,605,632
    const int block = 256;
    const int grid = (total + block - 1) / block;
    roi_pool_kernel<<<grid, block, 0, stream>>>(x, rois, out);
}